// Round 4
// baseline (341.388 us; speedup 1.0000x reference)
//
#include <hip/hip_runtime.h>
#include <hip/hip_fp16.h>
#include <hip/hip_bf16.h>

// SplineConv MI355X (gfx950). fp32 in/out. R15:
//  - R14 container fault root-caused: CSR record loads used (uint4*) on
//    bket+quad*8 where startA[node] has arbitrary parity -> 8B-aligned
//    global_load_dwordx4 -> memory violation. FIX: 8x uint2 loads (natural
//    alignment; LLVM cannot re-merge without provable align-16).
//  - everything else unchanged from R14:
//     * no window/bpermute: records loaded directly from CSR per quad
//     * gather burst FORCED via inline asm: 2x16 global_load_ushort,
//       "=&v" outputs (32 live VGPRs), one s_waitcnt vmcnt(0) pass-through
//       ("+v" ties = rule-18-safe consumer deps). Hat VALU overlaps latency.
//     * garbage-tail safety: min(col,49999) clamp + cndmask hat select.
//  - prep path UNCHANGED from R13 (memset + k_prep + k_sort).
// Scatter-as-GEMM per node wave + root-folded MFMA epilogue (R9/R10-validated).

#define NN    50000
#define EE    1600000
#define NPB   16
#define KD    1664           // 26*64: 25 conv slices + root slice
#define ASTB  1672           // accS row stride (bf16 elems)

#define NB    391            // coarse buckets = ceil(NN/128)
#define NSH   4              // shards per bucket
#define CCAP  1280           // per-shard capacity (lambda=1024, +8 sigma)
#define CSTR  16             // ccur stride in u32 (64B pad -> own cacheline)

// prep-kernel grid sections (edges first so they start immediately)
#define REC_B 6250           // EE/256 exactly
#define XB_B  1563           // ceil(NN*64/8/256)
#define WT_B  104            // 64*KD/4/256 exactly

typedef unsigned short ushort_t;
typedef __attribute__((ext_vector_type(8))) short short8;
typedef __attribute__((ext_vector_type(4))) float f32x4;

static __device__ __forceinline__ ushort_t f2bf(float f) {
  union { float f; unsigned u; } v; v.f = f;
  return (ushort_t)((v.u + 0x7fffu + ((v.u >> 16) & 1u)) >> 16);  // RNE
}
static __device__ __forceinline__ unsigned pk2bf(float a, float b) {
  __hip_bfloat162 h = __float22bfloat162_rn(make_float2(a, b));   // v_cvt_pk_bf16_f32
  union { __hip_bfloat162 h; unsigned u; } cv; cv.h = h; return cv.u;
}
union S8 { short8 s; unsigned u[4]; };

// ---------------- K: fused pass A. Sections: [0,REC_B) edges; [.., +XB_B) xb; rest wt.
__global__ __launch_bounds__(256) void k_prep(
    const int* __restrict__ ei, const float* __restrict__ pseudo,
    int* __restrict__ ccur, uint2* __restrict__ coarse,
    const float* __restrict__ x, ushort_t* __restrict__ xb,
    const float* __restrict__ w, const float* __restrict__ root,
    ushort_t* __restrict__ wt, int useXB) {
  const int b = blockIdx.x;
  const int tid = threadIdx.x;
  if (b < REC_B) {
    // ---- coarse scatter: record {col(u16) | row7(u8)<<16, fp16(v0)|fp16(v1)<<16}
    int e = b * 256 + tid;                    // EE == REC_B*256 exactly
    int row = ei[e], col = ei[EE + e];
    float2 pv = ((const float2*)pseudo)[e];
    float v0 = pv.x * 4.0f, v1 = pv.y * 4.0f;
    unsigned h0 = __half_as_ushort(__float2half(v0));
    unsigned h1 = __half_as_ushort(__float2half(v1));
    int c4 = (row >> 7) * NSH + (tid & (NSH - 1));
    int slot = atomicAdd(&ccur[c4 * CSTR], 1);
    if (slot < CCAP)                          // P(overflow) ~ 0 (8 sigma)
      coarse[(size_t)c4 * CCAP + slot] =
          make_uint2((unsigned)col | ((unsigned)(row & 127) << 16), h0 | (h1 << 16));
  } else if (b < REC_B + XB_B) {
    // ---- xb = bf16(x), 8 elems/thread (RNE identical to f2bf)
    if (!useXB) return;
    int t = (b - REC_B) * 256 + tid;
    if (t < NN * 8) {
      const float4* xp = (const float4*)x + (size_t)t * 2;
      float4 aa = xp[0], bb = xp[1];
      S8 o;
      o.u[0] = pk2bf(aa.x, aa.y); o.u[1] = pk2bf(aa.z, aa.w);
      o.u[2] = pk2bf(bb.x, bb.y); o.u[3] = pk2bf(bb.z, bb.w);
      ((short8*)xb)[t] = o.s;
    }
  } else {
    // ---- wt[o*1664+k]: k<1600 -> weight[k*64+o]; tail -> root[(k-1600)*64+o]
    int t = (b - REC_B - XB_B) * 256 + tid;
    int idx = t * 4;                          // KD%4==0 -> same o for all 4
    if (idx < 64 * KD) {
      int o = idx / KD, k = idx - o * KD;
#pragma unroll
      for (int q = 0; q < 4; ++q) {
        int kk = k + q;
        wt[idx + q] = (kk < 1600) ? f2bf(w[kk * 64 + o]) : f2bf(root[(kk - 1600) * 64 + o]);
      }
    }
  }
}

// ---------------- K: pass B. 1 block per coarse bucket -> exact CSR.
__global__ __launch_bounds__(256) void k_sort(
    const int* __restrict__ ccur, const uint2* __restrict__ coarse,
    uint2* __restrict__ recs, int* __restrict__ startA, int* __restrict__ degA) {
  __shared__ int cnt[128], lpos[128], scn[128], red[256];
  const int c = blockIdx.x, tid = threadIdx.x;
  if (tid < 128) cnt[tid] = 0;
  // base = total edges in buckets < c (read 64B-padded counters, L2-hot)
  const int pc = c * NSH;
  int a = 0;
  for (int i = tid; i < pc; i += 256) a += min(ccur[i * CSTR], CCAP);
  red[tid] = a;
  __syncthreads();
  for (int s = 128; s > 0; s >>= 1) { if (tid < s) red[tid] += red[tid + s]; __syncthreads(); }
  const int base = red[0];
  // count phase (LDS atomics over 128 rows)
  for (int s = 0; s < NSH; ++s) {
    int n = min(ccur[(pc + s) * CSTR], CCAP);
    const uint2* seg = coarse + (size_t)(pc + s) * CCAP;
    for (int i = tid; i < n; i += 256) atomicAdd(&cnt[(seg[i].x >> 16) & 127], 1);
  }
  __syncthreads();
  // inclusive scan (Hillis-Steele, 128 lanes)
  if (tid < 128) scn[tid] = cnt[tid];
  __syncthreads();
  for (int ofs = 1; ofs < 128; ofs <<= 1) {
    int v = 0;
    if (tid < 128 && tid >= ofs) v = scn[tid - ofs];
    __syncthreads();
    if (tid < 128 && tid >= ofs) scn[tid] += v;
    __syncthreads();
  }
  if (tid < 128) {
    int excl = scn[tid] - cnt[tid];
    lpos[tid] = base + excl;
    int row = c * 128 + tid;
    if (row < NN) { startA[row] = base + excl; degA[row] = cnt[tid]; }
  }
  __syncthreads();
  // scatter to exact CSR slots
  for (int s = 0; s < NSH; ++s) {
    int n = min(ccur[(pc + s) * CSTR], CCAP);
    const uint2* seg = coarse + (size_t)(pc + s) * CCAP;
    for (int i = tid; i < n; i += 256) {
      uint2 r = seg[i];
      int dst = atomicAdd(&lpos[(r.x >> 16) & 127], 1);
      recs[dst] = make_uint2(r.x & 0xFFFFu, r.y);
    }
  }
}

// ---------------- forced 32-load gather burst (XBF path). vo[i] = byte offset of
// row i's element for this lane; loads at +0/+32/+64/+96 (f = m15 + 16t).
static __device__ __forceinline__ void gather32(
    const ushort_t* __restrict__ xb, const unsigned* vo, unsigned (&g)[4][8]) {
  asm volatile(
      "global_load_ushort %[g00], %[a0], %[sb]\n\t"
      "global_load_ushort %[g10], %[a0], %[sb] offset:32\n\t"
      "global_load_ushort %[g20], %[a0], %[sb] offset:64\n\t"
      "global_load_ushort %[g30], %[a0], %[sb] offset:96\n\t"
      "global_load_ushort %[g01], %[a1], %[sb]\n\t"
      "global_load_ushort %[g11], %[a1], %[sb] offset:32\n\t"
      "global_load_ushort %[g21], %[a1], %[sb] offset:64\n\t"
      "global_load_ushort %[g31], %[a1], %[sb] offset:96\n\t"
      "global_load_ushort %[g02], %[a2], %[sb]\n\t"
      "global_load_ushort %[g12], %[a2], %[sb] offset:32\n\t"
      "global_load_ushort %[g22], %[a2], %[sb] offset:64\n\t"
      "global_load_ushort %[g32], %[a2], %[sb] offset:96\n\t"
      "global_load_ushort %[g03], %[a3], %[sb]\n\t"
      "global_load_ushort %[g13], %[a3], %[sb] offset:32\n\t"
      "global_load_ushort %[g23], %[a3], %[sb] offset:64\n\t"
      "global_load_ushort %[g33], %[a3], %[sb] offset:96\n\t"
      : [g00] "=&v"(g[0][0]), [g10] "=&v"(g[1][0]), [g20] "=&v"(g[2][0]), [g30] "=&v"(g[3][0]),
        [g01] "=&v"(g[0][1]), [g11] "=&v"(g[1][1]), [g21] "=&v"(g[2][1]), [g31] "=&v"(g[3][1]),
        [g02] "=&v"(g[0][2]), [g12] "=&v"(g[1][2]), [g22] "=&v"(g[2][2]), [g32] "=&v"(g[3][2]),
        [g03] "=&v"(g[0][3]), [g13] "=&v"(g[1][3]), [g23] "=&v"(g[2][3]), [g33] "=&v"(g[3][3])
      : [a0] "v"(vo[0]), [a1] "v"(vo[1]), [a2] "v"(vo[2]), [a3] "v"(vo[3]), [sb] "s"(xb));
  asm volatile(
      "global_load_ushort %[g04], %[a4], %[sb]\n\t"
      "global_load_ushort %[g14], %[a4], %[sb] offset:32\n\t"
      "global_load_ushort %[g24], %[a4], %[sb] offset:64\n\t"
      "global_load_ushort %[g34], %[a4], %[sb] offset:96\n\t"
      "global_load_ushort %[g05], %[a5], %[sb]\n\t"
      "global_load_ushort %[g15], %[a5], %[sb] offset:32\n\t"
      "global_load_ushort %[g25], %[a5], %[sb] offset:64\n\t"
      "global_load_ushort %[g35], %[a5], %[sb] offset:96\n\t"
      "global_load_ushort %[g06], %[a6], %[sb]\n\t"
      "global_load_ushort %[g16], %[a6], %[sb] offset:32\n\t"
      "global_load_ushort %[g26], %[a6], %[sb] offset:64\n\t"
      "global_load_ushort %[g36], %[a6], %[sb] offset:96\n\t"
      "global_load_ushort %[g07], %[a7], %[sb]\n\t"
      "global_load_ushort %[g17], %[a7], %[sb] offset:32\n\t"
      "global_load_ushort %[g27], %[a7], %[sb] offset:64\n\t"
      "global_load_ushort %[g37], %[a7], %[sb] offset:96\n\t"
      : [g04] "=&v"(g[0][4]), [g14] "=&v"(g[1][4]), [g24] "=&v"(g[2][4]), [g34] "=&v"(g[3][4]),
        [g05] "=&v"(g[0][5]), [g15] "=&v"(g[1][5]), [g25] "=&v"(g[2][5]), [g35] "=&v"(g[3][5]),
        [g06] "=&v"(g[0][6]), [g16] "=&v"(g[1][6]), [g26] "=&v"(g[2][6]), [g36] "=&v"(g[3][6]),
        [g07] "=&v"(g[0][7]), [g17] "=&v"(g[1][7]), [g27] "=&v"(g[2][7]), [g37] "=&v"(g[3][7])
      : [a4] "v"(vo[4]), [a5] "v"(vo[5]), [a6] "v"(vo[6]), [a7] "v"(vo[7]), [sb] "s"(xb));
}
static __device__ __forceinline__ void gather32_wait(unsigned (&g)[4][8]) {
  asm volatile("s_waitcnt vmcnt(0)"
               : "+v"(g[0][0]), "+v"(g[1][0]), "+v"(g[2][0]), "+v"(g[3][0]),
                 "+v"(g[0][1]), "+v"(g[1][1]), "+v"(g[2][1]), "+v"(g[3][1]),
                 "+v"(g[0][2]), "+v"(g[1][2]), "+v"(g[2][2]), "+v"(g[3][2]),
                 "+v"(g[0][3]), "+v"(g[1][3]), "+v"(g[2][3]), "+v"(g[3][3]));
  asm volatile(""   // ordered after the vmcnt(0) above; creates consumer deps
               : "+v"(g[0][4]), "+v"(g[1][4]), "+v"(g[2][4]), "+v"(g[3][4]),
                 "+v"(g[0][5]), "+v"(g[1][5]), "+v"(g[2][5]), "+v"(g[3][5]),
                 "+v"(g[0][6]), "+v"(g[1][6]), "+v"(g[2][6]), "+v"(g[3][6]),
                 "+v"(g[0][7]), "+v"(g[1][7]), "+v"(g[2][7]), "+v"(g[3][7]));
}

// ---------------- one K=32 edge chunk: records rq (8 recs for this quad), base kb.
template <bool XBF>
static __device__ __forceinline__ void do_chunk(
    const uint2 (&rq)[8], int kb, int m, int quad, int m15,
    float r0f, float c0f, float r1f, float c1f,
    const ushort_t* __restrict__ xb, const float* __restrict__ x,
    f32x4 (&acc)[2][4]) {
  unsigned cj[8], pj[8];
#pragma unroll
  for (int j = 0; j < 8; ++j) {
    cj[j] = min(rq[j].x, 49999u);             // clamp garbage tail (addr safety)
    pj[j] = rq[j].y;
  }
  unsigned g[4][8];
  float gf[4][8];
  if (XBF) {
    unsigned vo[8];
#pragma unroll
    for (int j = 0; j < 8; ++j) vo[j] = (cj[j] << 7) + (unsigned)(m15 << 1);
    gather32(xb, vo, g);                      // 32 loads in flight
  } else {
#pragma unroll
    for (int j = 0; j < 8; ++j) {
      const float* xr = x + (size_t)cj[j] * 64 + m15;
      gf[0][j] = xr[0]; gf[1][j] = xr[16]; gf[2][j] = xr[32]; gf[3][j] = xr[48];
    }
  }
  // ---- hats (VALU) overlap the gather latency; cndmask select (NaN-safe)
  S8 aT0, aT1, bT[4];
#pragma unroll
  for (int p = 0; p < 4; ++p) {
    float a0[2], a1[2];
#pragma unroll
    for (int q = 0; q < 2; ++q) {
      int j = 2 * p + q;
      unsigned pv = pj[j];
      float v0 = __half2float(__ushort_as_half((ushort_t)(pv & 0xFFFFu)));
      float v1 = __half2float(__ushort_as_half((ushort_t)(pv >> 16)));
      bool ok = (kb + quad * 8 + j) < m;
      float p0 = fmaxf(0.f, 1.f - fabsf(v0 - r0f)) * fmaxf(0.f, 1.f - fabsf(v1 - c0f));
      float p1 = fmaxf(0.f, 1.f - fabsf(v0 - r1f)) * fmaxf(0.f, 1.f - fabsf(v1 - c1f));
      a0[q] = ok ? p0 : 0.0f;
      a1[q] = ok ? p1 : 0.0f;
    }
    aT0.u[p] = pk2bf(a0[0], a0[1]);
    aT1.u[p] = pk2bf(a1[0], a1[1]);
  }
  if (XBF) gather32_wait(g);
#pragma unroll
  for (int p = 0; p < 4; ++p)
#pragma unroll
    for (int t = 0; t < 4; ++t)
      bT[t].u[p] = XBF ? (g[t][2 * p] | (g[t][2 * p + 1] << 16))
                       : pk2bf(gf[t][2 * p], gf[t][2 * p + 1]);
  __builtin_amdgcn_s_setprio(1);
#pragma unroll
  for (int t = 0; t < 4; ++t) {
    acc[0][t] = __builtin_amdgcn_mfma_f32_16x16x32_bf16(aT0.s, bT[t].s, acc[0][t], 0, 0, 0);
    acc[1][t] = __builtin_amdgcn_mfma_f32_16x16x32_bf16(aT1.s, bT[t].s, acc[1][t], 0, 0, 0);
  }
  __builtin_amdgcn_s_setprio(0);
}

// ---------------- K: main fused. 1 block = 16 nodes; wave w owns node nb+w.
template <bool XBF>
__global__ __launch_bounds__(1024, 4) void k_main(
    const uint2* __restrict__ recs, const int* __restrict__ startA,
    const int* __restrict__ degA,
    const float* __restrict__ x, const ushort_t* __restrict__ xb,
    const ushort_t* __restrict__ wt, const float* __restrict__ bias,
    float* __restrict__ out) {
  __shared__ ushort_t accS[NPB * ASTB];   // 53.5 KB, bf16, MFMA-A layout
  __shared__ float    outp[4 * NPB * 64]; // 16 KB, per-kh partials
  __shared__ float    sinv[NPB];
  const int tid = threadIdx.x;
  const int lane = tid & 63;
  const int w = tid >> 6;                 // wave id = node-in-block
  const int node = blockIdx.x * NPB + w;

  const int m = degA[node];               // exact degree (uncapped)
  const float dcf = (float)max(m, 1);
  if (lane == 0) sinv[w] = 1.0f / dcf;
  // root slice: accS[w][1600+i] = bf16(x[node][i] * dc); (x*dc)@root / dc = x@root
  accS[w * ASTB + 1600 + lane] = f2bf(x[(size_t)node * 64 + lane] * dcf);

  const int m15 = lane & 15, quad = lane >> 4;
  const float r0f = (float)(m15 / 5),        c0f = (float)(m15 % 5);
  const float r1f = (float)((16 + m15) / 5), c1f = (float)((16 + m15) % 5);

  f32x4 acc[2][4];                        // [mtile][ntile]
#pragma unroll
  for (int a = 0; a < 2; ++a)
#pragma unroll
    for (int b = 0; b < 4; ++b) acc[a][b] = (f32x4){0.f, 0.f, 0.f, 0.f};

  // ---- A-fragment records: contiguous run per quad, loaded DIRECTLY from CSR
  // as 8x uint2 (8B-aligned ALWAYS; startA has arbitrary parity so uint4 would
  // be a misaligned dwordx4 -> fault). Both chunks issue up-front; tails past
  // deg read in-bounds garbage (next node / coarse) -> clamped + hat-masked.
  const uint2* bket = recs + startA[node];
  uint2 rq0[8], rq1[8];
#pragma unroll
  for (int j = 0; j < 8; ++j) {
    rq0[j] = bket[quad * 8 + j];
    rq1[j] = bket[32 + quad * 8 + j];
  }
  if (m > 0)
    do_chunk<XBF>(rq0, 0, m, quad, m15, r0f, c0f, r1f, c1f, xb, x, acc);
  if (m > 32)
    do_chunk<XBF>(rq1, 32, m, quad, m15, r0f, c0f, r1f, c1f, xb, x, acc);
  for (int e0 = 64; e0 < m; e0 += 32) {   // rare: deg > 64
    uint2 rqx[8];
#pragma unroll
    for (int j = 0; j < 8; ++j) rqx[j] = bket[e0 + quad * 8 + j];
    do_chunk<XBF>(rqx, e0, m, quad, m15, r0f, c0f, r1f, c1f, xb, x, acc);
  }

  // spill acc -> accS; D layout: kp = mt*16 + quad*4 + r, f = nt*16 + m15
#pragma unroll
  for (int mt = 0; mt < 2; ++mt)
#pragma unroll
    for (int r = 0; r < 4; ++r) {
      int kp = mt * 16 + quad * 4 + r;
      if (kp < 25) {
#pragma unroll
        for (int nt = 0; nt < 4; ++nt)
          accS[w * ASTB + kp * 64 + nt * 16 + m15] = f2bf(acc[mt][nt][r]);
      }
    }
  __syncthreads();

  {  // MFMA epilogue (R8-R10 verified): D[16 nodes][64] = accS[16][1664] @ wt^T
    const int ntile = w & 3, kh = w >> 2;
    const int m2 = lane & 15, quad2 = lane >> 4;
    const int nn2 = ntile * 16 + m2;
    f32x4 d = {0.0f, 0.0f, 0.0f, 0.0f};
    const ushort_t* ab = &accS[m2 * ASTB + kh * 416 + quad2 * 8];
    const ushort_t* wb = &wt[(size_t)nn2 * KD + kh * 416 + quad2 * 8];
    for (int kk = 0; kk < 13; ++kk) {
      short8 af = *(const short8*)(ab + kk * 32);
      short8 bf = *(const short8*)(wb + kk * 32);
      d = __builtin_amdgcn_mfma_f32_16x16x32_bf16(af, bf, d, 0, 0, 0);
    }
#pragma unroll
    for (int r = 0; r < 4; ++r)
      outp[kh * (NPB * 64) + (quad2 * 4 + r) * 64 + ntile * 16 + m2] = d[r];
  }
  __syncthreads();

  {  // final: out = (conv + x*dc@root) * (1/dc) + bias
    float conv = outp[0 * (NPB * 64) + w * 64 + lane]
               + outp[1 * (NPB * 64) + w * 64 + lane]
               + outp[2 * (NPB * 64) + w * 64 + lane]
               + outp[3 * (NPB * 64) + w * 64 + lane];
    out[(size_t)node * 64 + lane] = conv * sinv[w] + bias[lane];
  }
}

// ---------------- sentinel: unambiguous "workspace too small" signature
__global__ void k_sentinel(float* __restrict__ out) {
  int i = blockIdx.x * 256 + threadIdx.x;
  if (i < NN * 64) out[i] = 1000.0f;
}

extern "C" void kernel_launch(void* const* d_in, const int* in_sizes, int n_in,
                              void* d_out, int out_size, void* d_ws, size_t ws_size,
                              hipStream_t stream) {
  const float* x      = (const float*)d_in[0];
  const int*   ei     = (const int*)d_in[1];
  const float* pseudo = (const float*)d_in[2];
  const float* w      = (const float*)d_in[3];
  const float* root   = (const float*)d_in[4];
  const float* bias   = (const float*)d_in[5];
  float* out = (float*)d_out;
  (void)in_sizes; (void)n_in; (void)out_size;

  char* ws = (char*)d_ws;
  size_t off = 0;
  auto alloc = [&](size_t bytes) { size_t r = off; off += (bytes + 511) & ~(size_t)511; return r; };
  ushort_t* wt     = (ushort_t*)(ws + alloc((size_t)64 * KD * 2));          // 213 KB
  int*      ccur   = (int*)(ws + alloc((size_t)NB * NSH * CSTR * 4));       // 100 KB
  int*      startA = (int*)(ws + alloc((size_t)NN * 4));                    // 200 KB
  int*      degA   = (int*)(ws + alloc((size_t)NN * 4));                    // 200 KB
  uint2*    recs   = (uint2*)(ws + alloc((size_t)EE * 8));                  // 12.8 MB
  uint2*    coarse = (uint2*)(ws + alloc((size_t)NB * NSH * CCAP * 8));     // 16.0 MB
  size_t baseNeed  = off;
  ushort_t* xb     = (ushort_t*)(ws + alloc((size_t)NN * 64 * 2));          // 6.4 MB (optional)
  size_t fullNeed  = off;

  if (ws_size < baseNeed) {
    k_sentinel<<<(NN * 64 + 255) / 256, 256, 0, stream>>>(out);
    return;
  }
  const int useXB = (ws_size >= fullNeed) ? 1 : 0;

  hipMemsetAsync(ccur, 0, (size_t)NB * NSH * CSTR * 4, stream);
  k_prep<<<REC_B + XB_B + WT_B, 256, 0, stream>>>(ei, pseudo, ccur, coarse,
                                                  x, xb, w, root, wt, useXB);
  k_sort<<<NB, 256, 0, stream>>>(ccur, coarse, recs, startA, degA);
  if (useXB)
    k_main<true><<<NN / NPB, 1024, 0, stream>>>(recs, startA, degA, x, xb, wt, bias, out);
  else
    k_main<false><<<NN / NPB, 1024, 0, stream>>>(recs, startA, degA, x, xb, wt, bias, out);
}

// Round 5
// 316.379 us; speedup vs baseline: 1.0790x; 1.0790x over previous
//
#include <hip/hip_runtime.h>
#include <hip/hip_fp16.h>
#include <hip/hip_bf16.h>

// SplineConv MI355X (gfx950). fp32 in/out. R16:
//  - R15 post-mortem: forced-asm gather spilled (52 arch VGPR for 40+ asm regs)
//    and regressed. asm DELETED; gathers back to compiler-scheduled (R13-best).
//  - New model: 32 AGPR acc + ~52 VGPR = 84 unified -> 128-granule -> 16 waves/CU
//    = ONE 16-wave block resident; per-block prologue (nfo->recs->gather) and
//    epilogue (13 serial dependent wt L2 loads) latency runs UNHIDDEN x12.2
//    rounds. That invariant is the ~150us, not the gather schedule.
//  - Fix within the reg granule: 512-thread blocks (8 waves, 2 nodes/wave,
//    still NPB=16 nodes/block) -> TWO blocks resident per CU -> cross-block
//    latency overlap. LDS cut to ~62KB (epilogue 8 waves x 2 kh x 26 kk,
//    outp 16->8KB) so 2 blocks fit any plausible LDS limit.
//  - Epilogue wt loads: depth-6 register prefetch (statically indexed via full
//    unroll; rule-20-safe) to break the 26-step serial L2 chain.
//  - k_sort now emits packed nfo[node]={start,deg} (one 8B load in k_main).
// Scatter-as-GEMM per node wave + root-folded MFMA epilogue (R9/R10-validated).

#define NN    50000
#define EE    1600000
#define NPB   16             // nodes per block (8 waves x 2 nodes)
#define KD    1664           // 26*64: 25 conv slices + root slice
#define ASTB  1672           // accS row stride (bf16 elems)

#define NB    391            // coarse buckets = ceil(NN/128)
#define NSH   4              // shards per bucket
#define CCAP  1280           // per-shard capacity (lambda=1024, +8 sigma)
#define CSTR  16             // ccur stride in u32 (64B pad -> own cacheline)

// prep-kernel grid sections (edges first so they start immediately)
#define REC_B 6250           // EE/256 exactly
#define XB_B  1563           // ceil(NN*64/8/256)
#define WT_B  104            // 64*KD/4/256 exactly

typedef unsigned short ushort_t;
typedef __attribute__((ext_vector_type(8))) short short8;
typedef __attribute__((ext_vector_type(4))) float f32x4;

static __device__ __forceinline__ ushort_t f2bf(float f) {
  union { float f; unsigned u; } v; v.f = f;
  return (ushort_t)((v.u + 0x7fffu + ((v.u >> 16) & 1u)) >> 16);  // RNE
}
static __device__ __forceinline__ unsigned pk2bf(float a, float b) {
  __hip_bfloat162 h = __float22bfloat162_rn(make_float2(a, b));   // v_cvt_pk_bf16_f32
  union { __hip_bfloat162 h; unsigned u; } cv; cv.h = h; return cv.u;
}
union S8 { short8 s; unsigned u[4]; };

// ---------------- K: fused pass A. Sections: [0,REC_B) edges; [.., +XB_B) xb; rest wt.
__global__ __launch_bounds__(256) void k_prep(
    const int* __restrict__ ei, const float* __restrict__ pseudo,
    int* __restrict__ ccur, uint2* __restrict__ coarse,
    const float* __restrict__ x, ushort_t* __restrict__ xb,
    const float* __restrict__ w, const float* __restrict__ root,
    ushort_t* __restrict__ wt, int useXB) {
  const int b = blockIdx.x;
  const int tid = threadIdx.x;
  if (b < REC_B) {
    // ---- coarse scatter: record {col(u16) | row7(u8)<<16, fp16(v0)|fp16(v1)<<16}
    int e = b * 256 + tid;                    // EE == REC_B*256 exactly
    int row = ei[e], col = ei[EE + e];
    float2 pv = ((const float2*)pseudo)[e];
    float v0 = pv.x * 4.0f, v1 = pv.y * 4.0f;
    unsigned h0 = __half_as_ushort(__float2half(v0));
    unsigned h1 = __half_as_ushort(__float2half(v1));
    int c4 = (row >> 7) * NSH + (tid & (NSH - 1));
    int slot = atomicAdd(&ccur[c4 * CSTR], 1);
    if (slot < CCAP)                          // P(overflow) ~ 0 (8 sigma)
      coarse[(size_t)c4 * CCAP + slot] =
          make_uint2((unsigned)col | ((unsigned)(row & 127) << 16), h0 | (h1 << 16));
  } else if (b < REC_B + XB_B) {
    // ---- xb = bf16(x), 8 elems/thread (RNE identical to f2bf)
    if (!useXB) return;
    int t = (b - REC_B) * 256 + tid;
    if (t < NN * 8) {
      const float4* xp = (const float4*)x + (size_t)t * 2;
      float4 aa = xp[0], bb = xp[1];
      S8 o;
      o.u[0] = pk2bf(aa.x, aa.y); o.u[1] = pk2bf(aa.z, aa.w);
      o.u[2] = pk2bf(bb.x, bb.y); o.u[3] = pk2bf(bb.z, bb.w);
      ((short8*)xb)[t] = o.s;
    }
  } else {
    // ---- wt[o*1664+k]: k<1600 -> weight[k*64+o]; tail -> root[(k-1600)*64+o]
    int t = (b - REC_B - XB_B) * 256 + tid;
    int idx = t * 4;                          // KD%4==0 -> same o for all 4
    if (idx < 64 * KD) {
      int o = idx / KD, k = idx - o * KD;
#pragma unroll
      for (int q = 0; q < 4; ++q) {
        int kk = k + q;
        wt[idx + q] = (kk < 1600) ? f2bf(w[kk * 64 + o]) : f2bf(root[(kk - 1600) * 64 + o]);
      }
    }
  }
}

// ---------------- K: pass B. 1 block per coarse bucket -> exact CSR + packed nfo.
__global__ __launch_bounds__(256) void k_sort(
    const int* __restrict__ ccur, const uint2* __restrict__ coarse,
    uint2* __restrict__ recs, uint2* __restrict__ nfo) {
  __shared__ int cnt[128], lpos[128], scn[128], red[256];
  const int c = blockIdx.x, tid = threadIdx.x;
  if (tid < 128) cnt[tid] = 0;
  // base = total edges in buckets < c (read 64B-padded counters, L2-hot)
  const int pc = c * NSH;
  int a = 0;
  for (int i = tid; i < pc; i += 256) a += min(ccur[i * CSTR], CCAP);
  red[tid] = a;
  __syncthreads();
  for (int s = 128; s > 0; s >>= 1) { if (tid < s) red[tid] += red[tid + s]; __syncthreads(); }
  const int base = red[0];
  // count phase (LDS atomics over 128 rows)
  for (int s = 0; s < NSH; ++s) {
    int n = min(ccur[(pc + s) * CSTR], CCAP);
    const uint2* seg = coarse + (size_t)(pc + s) * CCAP;
    for (int i = tid; i < n; i += 256) atomicAdd(&cnt[(seg[i].x >> 16) & 127], 1);
  }
  __syncthreads();
  // inclusive scan (Hillis-Steele, 128 lanes)
  if (tid < 128) scn[tid] = cnt[tid];
  __syncthreads();
  for (int ofs = 1; ofs < 128; ofs <<= 1) {
    int v = 0;
    if (tid < 128 && tid >= ofs) v = scn[tid - ofs];
    __syncthreads();
    if (tid < 128 && tid >= ofs) scn[tid] += v;
    __syncthreads();
  }
  if (tid < 128) {
    int excl = scn[tid] - cnt[tid];
    lpos[tid] = base + excl;
    int row = c * 128 + tid;
    if (row < NN) nfo[row] = make_uint2((unsigned)(base + excl), (unsigned)cnt[tid]);
  }
  __syncthreads();
  // scatter to exact CSR slots
  for (int s = 0; s < NSH; ++s) {
    int n = min(ccur[(pc + s) * CSTR], CCAP);
    const uint2* seg = coarse + (size_t)(pc + s) * CCAP;
    for (int i = tid; i < n; i += 256) {
      uint2 r = seg[i];
      int dst = atomicAdd(&lpos[(r.x >> 16) & 127], 1);
      recs[dst] = make_uint2(r.x & 0xFFFFu, r.y);
    }
  }
}

// ---------------- one K=32 edge chunk: records rq (8 recs for this quad), base kb.
// Tail reads past deg are in-workspace garbage (recs is followed by coarse):
// col clamped for addr safety, hat zeroed by the ok-mask.
template <bool XBF>
static __device__ __forceinline__ void do_chunk(
    const uint2 (&rq)[8], int kb, int m, int quad, int m15,
    float r0f, float c0f, float r1f, float c1f,
    const ushort_t* __restrict__ xb, const float* __restrict__ x,
    f32x4 (&acc)[2][4]) {
  unsigned cj[8], pj[8];
#pragma unroll
  for (int j = 0; j < 8; ++j) {
    cj[j] = min(rq[j].x, (unsigned)(NN - 1));
    pj[j] = rq[j].y;
  }
  unsigned g[4][8];
  float gf[4][8];
  if (XBF) {
#pragma unroll
    for (int j = 0; j < 8; ++j) {
      const ushort_t* xr = xb + ((size_t)cj[j] << 6) + m15;
      g[0][j] = xr[0]; g[1][j] = xr[16]; g[2][j] = xr[32]; g[3][j] = xr[48];
    }
  } else {
#pragma unroll
    for (int j = 0; j < 8; ++j) {
      const float* xr = x + ((size_t)cj[j] << 6) + m15;
      gf[0][j] = xr[0]; gf[1][j] = xr[16]; gf[2][j] = xr[32]; gf[3][j] = xr[48];
    }
  }
  // ---- hats (VALU) overlap the gather latency; cndmask select (NaN-safe)
  S8 aT0, aT1, bT[4];
#pragma unroll
  for (int p = 0; p < 4; ++p) {
    float a0[2], a1[2];
#pragma unroll
    for (int q = 0; q < 2; ++q) {
      int j = 2 * p + q;
      unsigned pv = pj[j];
      float v0 = __half2float(__ushort_as_half((ushort_t)(pv & 0xFFFFu)));
      float v1 = __half2float(__ushort_as_half((ushort_t)(pv >> 16)));
      bool ok = (kb + quad * 8 + j) < m;
      float p0 = fmaxf(0.f, 1.f - fabsf(v0 - r0f)) * fmaxf(0.f, 1.f - fabsf(v1 - c0f));
      float p1 = fmaxf(0.f, 1.f - fabsf(v0 - r1f)) * fmaxf(0.f, 1.f - fabsf(v1 - c1f));
      a0[q] = ok ? p0 : 0.0f;
      a1[q] = ok ? p1 : 0.0f;
    }
    aT0.u[p] = pk2bf(a0[0], a0[1]);
    aT1.u[p] = pk2bf(a1[0], a1[1]);
  }
#pragma unroll
  for (int p = 0; p < 4; ++p)
#pragma unroll
    for (int t = 0; t < 4; ++t)
      bT[t].u[p] = XBF ? (g[t][2 * p] | (g[t][2 * p + 1] << 16))
                       : pk2bf(gf[t][2 * p], gf[t][2 * p + 1]);
  __builtin_amdgcn_s_setprio(1);
#pragma unroll
  for (int t = 0; t < 4; ++t) {
    acc[0][t] = __builtin_amdgcn_mfma_f32_16x16x32_bf16(aT0.s, bT[t].s, acc[0][t], 0, 0, 0);
    acc[1][t] = __builtin_amdgcn_mfma_f32_16x16x32_bf16(aT1.s, bT[t].s, acc[1][t], 0, 0, 0);
  }
  __builtin_amdgcn_s_setprio(0);
}

// ---------------- K: main fused. 1 block = 16 nodes, 8 waves x 2 nodes each.
// 512 threads + ~62KB LDS + <=128 unified regs -> TWO blocks resident per CU
// (cross-block prologue/epilogue latency overlap; was 1 block at R11-R15).
template <bool XBF>
__global__ __launch_bounds__(512, 4) void k_main(
    const uint2* __restrict__ recs, const uint2* __restrict__ nfo,
    const float* __restrict__ x, const ushort_t* __restrict__ xb,
    const ushort_t* __restrict__ wt, const float* __restrict__ bias,
    float* __restrict__ out) {
  __shared__ ushort_t accS[NPB * ASTB];   // 53.5 KB, bf16, MFMA-A layout
  __shared__ float    outp[2 * NPB * 64]; // 8 KB, per-kh partials (2 halves)
  __shared__ float    sinv[NPB];
  const int tid = threadIdx.x;
  const int lane = tid & 63;
  const int w = tid >> 6;                 // wave id in [0,8)
  const int nb = blockIdx.x * NPB;

  const int m15 = lane & 15, quad = lane >> 4;
  const float r0f = (float)(m15 / 5),        c0f = (float)(m15 % 5);
  const float r1f = (float)((16 + m15) / 5), c1f = (float)((16 + m15) % 5);

#pragma unroll
  for (int nd = 0; nd < 2; ++nd) {        // wave w owns nodes 2w, 2w+1 (serial)
    const int row = (w << 1) + nd;
    const int node = nb + row;
    const uint2 nf = nfo[node];           // packed {start, deg}, one 8B load
    const int m = (int)nf.y;
    const float dcf = (float)max(m, 1);
    if (lane == 0) sinv[row] = 1.0f / dcf;
    // root slice: accS[row][1600+i] = bf16(x[node][i]*dc); (x*dc)@root/dc = x@root
    accS[row * ASTB + 1600 + lane] = f2bf(x[(size_t)node * 64 + lane] * dcf);

    f32x4 acc[2][4];                      // [mtile][ntile], 32 AGPRs
#pragma unroll
    for (int a = 0; a < 2; ++a)
#pragma unroll
      for (int b = 0; b < 4; ++b) acc[a][b] = (f32x4){0.f, 0.f, 0.f, 0.f};

    const uint2* bket = recs + nf.x;
    for (int e0 = 0; e0 < m; e0 += 32) {  // K=32 edge chunks
      uint2 rq[8];                        // this quad's 8 records (8B-aligned loads)
#pragma unroll
      for (int j = 0; j < 8; ++j) rq[j] = bket[e0 + quad * 8 + j];
      do_chunk<XBF>(rq, e0, m, quad, m15, r0f, c0f, r1f, c1f, xb, x, acc);
    }

    // spill acc -> accS; D layout: kp = mt*16 + quad*4 + r, f = nt*16 + m15
#pragma unroll
    for (int mt = 0; mt < 2; ++mt)
#pragma unroll
      for (int r = 0; r < 4; ++r) {
        int kp = mt * 16 + quad * 4 + r;
        if (kp < 25) {
#pragma unroll
          for (int nt = 0; nt < 4; ++nt)
            accS[row * ASTB + kp * 64 + nt * 16 + m15] = f2bf(acc[mt][nt][r]);
        }
      }
  }
  __syncthreads();

  {  // MFMA epilogue: D[16 nodes][64] = accS[16][1664] @ wt^T
    // 8 waves: ntile = w&3 (output quarter), kh = w>>2 (K half, 26 kk each).
    // wt fragments prefetched depth-6 into statically-indexed regs (full
    // unroll -> kk%6 is compile-time; breaks the serial dependent-L2 chain).
    const int ntile = w & 3, kh = w >> 2;
    const int m2 = lane & 15, quad2 = lane >> 4;
    const int nn2 = ntile * 16 + m2;
    f32x4 d = {0.0f, 0.0f, 0.0f, 0.0f};
    const ushort_t* ab = &accS[m2 * ASTB + kh * 832 + quad2 * 8];
    const ushort_t* wb = &wt[(size_t)nn2 * KD + kh * 832 + quad2 * 8];
    short8 bfs[6];
#pragma unroll
    for (int kk = 0; kk < 6; ++kk) bfs[kk] = *(const short8*)(wb + kk * 32);
#pragma unroll
    for (int kk = 0; kk < 26; ++kk) {
      short8 af = *(const short8*)(ab + kk * 32);
      d = __builtin_amdgcn_mfma_f32_16x16x32_bf16(af, bfs[kk % 6], d, 0, 0, 0);
      if (kk + 6 < 26) bfs[kk % 6] = *(const short8*)(wb + (kk + 6) * 32);
    }
#pragma unroll
    for (int r = 0; r < 4; ++r)
      outp[kh * (NPB * 64) + (quad2 * 4 + r) * 64 + ntile * 16 + m2] = d[r];
  }
  __syncthreads();

  {  // final: out = (conv + x*dc@root) * (1/dc) + bias; 512 threads x 2 elems
#pragma unroll
    for (int h = 0; h < 2; ++h) {
      int i = h * 512 + tid;
      int nl = i >> 6, o = i & 63;
      float conv = outp[i] + outp[NPB * 64 + i];
      out[(size_t)(nb + nl) * 64 + o] = conv * sinv[nl] + bias[o];
    }
  }
}

// ---------------- sentinel: unambiguous "workspace too small" signature
__global__ void k_sentinel(float* __restrict__ out) {
  int i = blockIdx.x * 256 + threadIdx.x;
  if (i < NN * 64) out[i] = 1000.0f;
}

extern "C" void kernel_launch(void* const* d_in, const int* in_sizes, int n_in,
                              void* d_out, int out_size, void* d_ws, size_t ws_size,
                              hipStream_t stream) {
  const float* x      = (const float*)d_in[0];
  const int*   ei     = (const int*)d_in[1];
  const float* pseudo = (const float*)d_in[2];
  const float* w      = (const float*)d_in[3];
  const float* root   = (const float*)d_in[4];
  const float* bias   = (const float*)d_in[5];
  float* out = (float*)d_out;
  (void)in_sizes; (void)n_in; (void)out_size;

  char* ws = (char*)d_ws;
  size_t off = 0;
  auto alloc = [&](size_t bytes) { size_t r = off; off += (bytes + 511) & ~(size_t)511; return r; };
  ushort_t* wt     = (ushort_t*)(ws + alloc((size_t)64 * KD * 2));          // 213 KB
  int*      ccur   = (int*)(ws + alloc((size_t)NB * NSH * CSTR * 4));       // 100 KB
  uint2*    nfo    = (uint2*)(ws + alloc((size_t)NN * 8));                  // 400 KB
  uint2*    recs   = (uint2*)(ws + alloc((size_t)EE * 8));                  // 12.8 MB
  uint2*    coarse = (uint2*)(ws + alloc((size_t)NB * NSH * CCAP * 8));     // 16.0 MB
  size_t baseNeed  = off;
  ushort_t* xb     = (ushort_t*)(ws + alloc((size_t)NN * 64 * 2));          // 6.4 MB (optional)
  size_t fullNeed  = off;

  if (ws_size < baseNeed) {
    k_sentinel<<<(NN * 64 + 255) / 256, 256, 0, stream>>>(out);
    return;
  }
  const int useXB = (ws_size >= fullNeed) ? 1 : 0;

  hipMemsetAsync(ccur, 0, (size_t)NB * NSH * CSTR * 4, stream);
  k_prep<<<REC_B + XB_B + WT_B, 256, 0, stream>>>(ei, pseudo, ccur, coarse,
                                                  x, xb, w, root, wt, useXB);
  k_sort<<<NB, 256, 0, stream>>>(ccur, coarse, recs, nfo);
  if (useXB)
    k_main<true><<<NN / NPB, 512, 0, stream>>>(recs, nfo, x, xb, wt, bias, out);
  else
    k_main<false><<<NN / NPB, 512, 0, stream>>>(recs, nfo, x, xb, wt, bias, out);
}

// Round 6
// 316.056 us; speedup vs baseline: 1.0802x; 1.0010x over previous
//
#include <hip/hip_runtime.h>
#include <hip/hip_fp16.h>
#include <hip/hip_bf16.h>

// SplineConv MI355X (gfx950). fp32 in/out. R17:
//  - Diagnosis across R12-R16: all gather re-SCHEDULES landed at 145-162us;
//    none changed VMEM op count (32 ushort gathers + 8 rec loads per chunk).
//    Surviving theory: bound on vector-memory op throughput for scattered
//    narrow loads, not dependency latency.
//  - FEATURE PERMUTATION (exact): accS slot c <-> feature 4*(c&15)+(c>>4),
//    applied consistently to (a) B-fragment gather, (b) wt build, (c) root
//    slice. Lane m15's four tile-features become 4*m15..4*m15+3 = ONE 8B
//    dwordx2 gather per edge row: 32 -> 8 gathers/chunk (16 VMEM total,
//    was 40). Same bytes, same cache lines, spill/epilogue untouched.
//  - fp32 fallback gather likewise becomes one dwordx4.
//  - structure otherwise identical to R16 (512 thr, 8 waves x 2 nodes,
//    62KB LDS, 2 blocks/CU, depth-6 epilogue wt prefetch, packed nfo).
// Scatter-as-GEMM per node wave + root-folded MFMA epilogue (R9/R10-validated).

#define NN    50000
#define EE    1600000
#define NPB   16             // nodes per block (8 waves x 2 nodes)
#define KD    1664           // 26*64: 25 conv slices + root slice
#define ASTB  1672           // accS row stride (bf16 elems)

#define NB    391            // coarse buckets = ceil(NN/128)
#define NSH   4              // shards per bucket
#define CCAP  1280           // per-shard capacity (lambda=1024, +8 sigma)
#define CSTR  16             // ccur stride in u32 (64B pad -> own cacheline)

// prep-kernel grid sections (edges first so they start immediately)
#define REC_B 6250           // EE/256 exactly
#define XB_B  1563           // ceil(NN*64/8/256)
#define WT_B  104            // 64*KD/4/256 exactly

typedef unsigned short ushort_t;
typedef __attribute__((ext_vector_type(8))) short short8;
typedef __attribute__((ext_vector_type(4))) float f32x4;

static __device__ __forceinline__ ushort_t f2bf(float f) {
  union { float f; unsigned u; } v; v.f = f;
  return (ushort_t)((v.u + 0x7fffu + ((v.u >> 16) & 1u)) >> 16);  // RNE
}
static __device__ __forceinline__ unsigned pk2bf(float a, float b) {
  __hip_bfloat162 h = __float22bfloat162_rn(make_float2(a, b));   // v_cvt_pk_bf16_f32
  union { __hip_bfloat162 h; unsigned u; } cv; cv.h = h; return cv.u;
}
union S8 { short8 s; unsigned u[4]; };

// ---------------- K: fused pass A. Sections: [0,REC_B) edges; [.., +XB_B) xb; rest wt.
__global__ __launch_bounds__(256) void k_prep(
    const int* __restrict__ ei, const float* __restrict__ pseudo,
    int* __restrict__ ccur, uint2* __restrict__ coarse,
    const float* __restrict__ x, ushort_t* __restrict__ xb,
    const float* __restrict__ w, const float* __restrict__ root,
    ushort_t* __restrict__ wt, int useXB) {
  const int b = blockIdx.x;
  const int tid = threadIdx.x;
  if (b < REC_B) {
    // ---- coarse scatter: record {col(u16) | row7(u8)<<16, fp16(v0)|fp16(v1)<<16}
    int e = b * 256 + tid;                    // EE == REC_B*256 exactly
    int row = ei[e], col = ei[EE + e];
    float2 pv = ((const float2*)pseudo)[e];
    float v0 = pv.x * 4.0f, v1 = pv.y * 4.0f;
    unsigned h0 = __half_as_ushort(__float2half(v0));
    unsigned h1 = __half_as_ushort(__float2half(v1));
    int c4 = (row >> 7) * NSH + (tid & (NSH - 1));
    int slot = atomicAdd(&ccur[c4 * CSTR], 1);
    if (slot < CCAP)                          // P(overflow) ~ 0 (8 sigma)
      coarse[(size_t)c4 * CCAP + slot] =
          make_uint2((unsigned)col | ((unsigned)(row & 127) << 16), h0 | (h1 << 16));
  } else if (b < REC_B + XB_B) {
    // ---- xb = bf16(x), 8 elems/thread (RNE identical to f2bf)
    if (!useXB) return;
    int t = (b - REC_B) * 256 + tid;
    if (t < NN * 8) {
      const float4* xp = (const float4*)x + (size_t)t * 2;
      float4 aa = xp[0], bb = xp[1];
      S8 o;
      o.u[0] = pk2bf(aa.x, aa.y); o.u[1] = pk2bf(aa.z, aa.w);
      o.u[2] = pk2bf(bb.x, bb.y); o.u[3] = pk2bf(bb.z, bb.w);
      ((short8*)xb)[t] = o.s;
    }
  } else {
    // ---- wt with PERMUTED K-slots: slot c of group kp holds input-feature
    // fi = 4*(c&15) + (c>>4)  (matches B-fragment dwordx2 gather + spill slots)
    int t = (b - REC_B - XB_B) * 256 + tid;
    int idx = t * 4;                          // KD%4==0 -> same o for all 4
    if (idx < 64 * KD) {
      int o = idx / KD, k = idx - o * KD;
#pragma unroll
      for (int q = 0; q < 4; ++q) {
        int kk = k + q;
        int kp = kk >> 6, c = kk & 63;
        int fi = 4 * (c & 15) + (c >> 4);
        wt[idx + q] = (kp < 25) ? f2bf(w[(kp * 64 + fi) * 64 + o])
                                : f2bf(root[fi * 64 + o]);
      }
    }
  }
}

// ---------------- K: pass B. 1 block per coarse bucket -> exact CSR + packed nfo.
__global__ __launch_bounds__(256) void k_sort(
    const int* __restrict__ ccur, const uint2* __restrict__ coarse,
    uint2* __restrict__ recs, uint2* __restrict__ nfo) {
  __shared__ int cnt[128], lpos[128], scn[128], red[256];
  const int c = blockIdx.x, tid = threadIdx.x;
  if (tid < 128) cnt[tid] = 0;
  // base = total edges in buckets < c (read 64B-padded counters, L2-hot)
  const int pc = c * NSH;
  int a = 0;
  for (int i = tid; i < pc; i += 256) a += min(ccur[i * CSTR], CCAP);
  red[tid] = a;
  __syncthreads();
  for (int s = 128; s > 0; s >>= 1) { if (tid < s) red[tid] += red[tid + s]; __syncthreads(); }
  const int base = red[0];
  // count phase (LDS atomics over 128 rows)
  for (int s = 0; s < NSH; ++s) {
    int n = min(ccur[(pc + s) * CSTR], CCAP);
    const uint2* seg = coarse + (size_t)(pc + s) * CCAP;
    for (int i = tid; i < n; i += 256) atomicAdd(&cnt[(seg[i].x >> 16) & 127], 1);
  }
  __syncthreads();
  // inclusive scan (Hillis-Steele, 128 lanes)
  if (tid < 128) scn[tid] = cnt[tid];
  __syncthreads();
  for (int ofs = 1; ofs < 128; ofs <<= 1) {
    int v = 0;
    if (tid < 128 && tid >= ofs) v = scn[tid - ofs];
    __syncthreads();
    if (tid < 128 && tid >= ofs) scn[tid] += v;
    __syncthreads();
  }
  if (tid < 128) {
    int excl = scn[tid] - cnt[tid];
    lpos[tid] = base + excl;
    int row = c * 128 + tid;
    if (row < NN) nfo[row] = make_uint2((unsigned)(base + excl), (unsigned)cnt[tid]);
  }
  __syncthreads();
  // scatter to exact CSR slots
  for (int s = 0; s < NSH; ++s) {
    int n = min(ccur[(pc + s) * CSTR], CCAP);
    const uint2* seg = coarse + (size_t)(pc + s) * CCAP;
    for (int i = tid; i < n; i += 256) {
      uint2 r = seg[i];
      int dst = atomicAdd(&lpos[(r.x >> 16) & 127], 1);
      recs[dst] = make_uint2(r.x & 0xFFFFu, r.y);
    }
  }
}

// ---------------- one K=32 edge chunk: records rq (8 recs for this quad), base kb.
// Tail reads past deg are in-workspace garbage (recs is followed by coarse):
// col clamped for addr safety, hat zeroed by the ok-mask.
// B gather (permuted features): lane m15 reads feats 4*m15..4*m15+3 of each of
// its quad's 8 edge rows -> ONE dwordx2 (bf16) / dwordx4 (fp32) per row.
template <bool XBF>
static __device__ __forceinline__ void do_chunk(
    const uint2 (&rq)[8], int kb, int m, int quad, int m15,
    float r0f, float c0f, float r1f, float c1f,
    const ushort_t* __restrict__ xb, const float* __restrict__ x,
    f32x4 (&acc)[2][4]) {
  unsigned cj[8], pj[8];
#pragma unroll
  for (int j = 0; j < 8; ++j) {
    cj[j] = min(rq[j].x, (unsigned)(NN - 1));
    pj[j] = rq[j].y;
  }
  uint2 g[8];
  float gf[4][8];
  if (XBF) {
#pragma unroll
    for (int j = 0; j < 8; ++j)
      g[j] = *(const uint2*)(xb + ((size_t)cj[j] << 6) + (m15 << 2));
  } else {
#pragma unroll
    for (int j = 0; j < 8; ++j) {
      float4 v = *(const float4*)(x + ((size_t)cj[j] << 6) + (m15 << 2));
      gf[0][j] = v.x; gf[1][j] = v.y; gf[2][j] = v.z; gf[3][j] = v.w;
    }
  }
  // ---- hats (VALU) overlap the gather latency; cndmask select (NaN-safe)
  S8 aT0, aT1, bT[4];
#pragma unroll
  for (int p = 0; p < 4; ++p) {
    float a0[2], a1[2];
#pragma unroll
    for (int q = 0; q < 2; ++q) {
      int j = 2 * p + q;
      unsigned pv = pj[j];
      float v0 = __half2float(__ushort_as_half((ushort_t)(pv & 0xFFFFu)));
      float v1 = __half2float(__ushort_as_half((ushort_t)(pv >> 16)));
      bool ok = (kb + quad * 8 + j) < m;
      float p0 = fmaxf(0.f, 1.f - fabsf(v0 - r0f)) * fmaxf(0.f, 1.f - fabsf(v1 - c0f));
      float p1 = fmaxf(0.f, 1.f - fabsf(v0 - r1f)) * fmaxf(0.f, 1.f - fabsf(v1 - c1f));
      a0[q] = ok ? p0 : 0.0f;
      a1[q] = ok ? p1 : 0.0f;
    }
    aT0.u[p] = pk2bf(a0[0], a0[1]);
    aT1.u[p] = pk2bf(a1[0], a1[1]);
  }
  if (XBF) {
#pragma unroll
    for (int p = 0; p < 4; ++p) {
      bT[0].u[p] = (g[2 * p].x & 0xFFFFu) | (g[2 * p + 1].x << 16);
      bT[1].u[p] = (g[2 * p].x >> 16)     | (g[2 * p + 1].x & 0xFFFF0000u);
      bT[2].u[p] = (g[2 * p].y & 0xFFFFu) | (g[2 * p + 1].y << 16);
      bT[3].u[p] = (g[2 * p].y >> 16)     | (g[2 * p + 1].y & 0xFFFF0000u);
    }
  } else {
#pragma unroll
    for (int p = 0; p < 4; ++p)
#pragma unroll
      for (int t = 0; t < 4; ++t)
        bT[t].u[p] = pk2bf(gf[t][2 * p], gf[t][2 * p + 1]);
  }
  __builtin_amdgcn_s_setprio(1);
#pragma unroll
  for (int t = 0; t < 4; ++t) {
    acc[0][t] = __builtin_amdgcn_mfma_f32_16x16x32_bf16(aT0.s, bT[t].s, acc[0][t], 0, 0, 0);
    acc[1][t] = __builtin_amdgcn_mfma_f32_16x16x32_bf16(aT1.s, bT[t].s, acc[1][t], 0, 0, 0);
  }
  __builtin_amdgcn_s_setprio(0);
}

// ---------------- K: main fused. 1 block = 16 nodes, 8 waves x 2 nodes each.
// 512 threads + ~62KB LDS + <=128 unified regs -> TWO blocks resident per CU.
template <bool XBF>
__global__ __launch_bounds__(512, 4) void k_main(
    const uint2* __restrict__ recs, const uint2* __restrict__ nfo,
    const float* __restrict__ x, const ushort_t* __restrict__ xb,
    const ushort_t* __restrict__ wt, const float* __restrict__ bias,
    float* __restrict__ out) {
  __shared__ ushort_t accS[NPB * ASTB];   // 53.5 KB, bf16, MFMA-A layout
  __shared__ float    outp[2 * NPB * 64]; // 8 KB, per-kh partials (2 halves)
  __shared__ float    sinv[NPB];
  const int tid = threadIdx.x;
  const int lane = tid & 63;
  const int w = tid >> 6;                 // wave id in [0,8)
  const int nb = blockIdx.x * NPB;

  const int m15 = lane & 15, quad = lane >> 4;
  const float r0f = (float)(m15 / 5),        c0f = (float)(m15 % 5);
  const float r1f = (float)((16 + m15) / 5), c1f = (float)((16 + m15) % 5);
  const int fl = 4 * (lane & 15) + (lane >> 4);   // permuted feature for slot=lane

#pragma unroll
  for (int nd = 0; nd < 2; ++nd) {        // wave w owns nodes 2w, 2w+1 (serial)
    const int row = (w << 1) + nd;
    const int node = nb + row;
    const uint2 nf = nfo[node];           // packed {start, deg}, one 8B load
    const int m = (int)nf.y;
    const float dcf = (float)max(m, 1);
    if (lane == 0) sinv[row] = 1.0f / dcf;
    // root slice (permuted slots): accS[row][1600+c] = bf16(x[node][perm(c)]*dc)
    accS[row * ASTB + 1600 + lane] = f2bf(x[(size_t)node * 64 + fl] * dcf);

    f32x4 acc[2][4];                      // [mtile][ntile], 32 AGPRs
#pragma unroll
    for (int a = 0; a < 2; ++a)
#pragma unroll
      for (int b = 0; b < 4; ++b) acc[a][b] = (f32x4){0.f, 0.f, 0.f, 0.f};

    const uint2* bket = recs + nf.x;
    for (int e0 = 0; e0 < m; e0 += 32) {  // K=32 edge chunks
      uint2 rq[8];                        // this quad's 8 records (8B-aligned loads)
#pragma unroll
      for (int j = 0; j < 8; ++j) rq[j] = bket[e0 + quad * 8 + j];
      do_chunk<XBF>(rq, e0, m, quad, m15, r0f, c0f, r1f, c1f, xb, x, acc);
    }

    // spill acc -> accS; D layout: kp = mt*16 + quad*4 + r, slot = nt*16 + m15
#pragma unroll
    for (int mt = 0; mt < 2; ++mt)
#pragma unroll
      for (int r = 0; r < 4; ++r) {
        int kp = mt * 16 + quad * 4 + r;
        if (kp < 25) {
#pragma unroll
          for (int nt = 0; nt < 4; ++nt)
            accS[row * ASTB + kp * 64 + nt * 16 + m15] = f2bf(acc[mt][nt][r]);
        }
      }
  }
  __syncthreads();

  {  // MFMA epilogue: D[16 nodes][64] = accS[16][1664] @ wt^T
    // 8 waves: ntile = w&3 (output quarter), kh = w>>2 (K half, 26 kk each).
    // wt fragments prefetched depth-6 into statically-indexed regs.
    const int ntile = w & 3, kh = w >> 2;
    const int m2 = lane & 15, quad2 = lane >> 4;
    const int nn2 = ntile * 16 + m2;
    f32x4 d = {0.0f, 0.0f, 0.0f, 0.0f};
    const ushort_t* ab = &accS[m2 * ASTB + kh * 832 + quad2 * 8];
    const ushort_t* wb = &wt[(size_t)nn2 * KD + kh * 832 + quad2 * 8];
    short8 bfs[6];
#pragma unroll
    for (int kk = 0; kk < 6; ++kk) bfs[kk] = *(const short8*)(wb + kk * 32);
#pragma unroll
    for (int kk = 0; kk < 26; ++kk) {
      short8 af = *(const short8*)(ab + kk * 32);
      d = __builtin_amdgcn_mfma_f32_16x16x32_bf16(af, bfs[kk % 6], d, 0, 0, 0);
      if (kk + 6 < 26) bfs[kk % 6] = *(const short8*)(wb + (kk + 6) * 32);
    }
#pragma unroll
    for (int r = 0; r < 4; ++r)
      outp[kh * (NPB * 64) + (quad2 * 4 + r) * 64 + ntile * 16 + m2] = d[r];
  }
  __syncthreads();

  {  // final: out = (conv + x*dc@root) * (1/dc) + bias; 512 threads x 2 elems
#pragma unroll
    for (int h = 0; h < 2; ++h) {
      int i = h * 512 + tid;
      int nl = i >> 6, o = i & 63;
      float conv = outp[i] + outp[NPB * 64 + i];
      out[(size_t)(nb + nl) * 64 + o] = conv * sinv[nl] + bias[o];
    }
  }
}

// ---------------- sentinel: unambiguous "workspace too small" signature
__global__ void k_sentinel(float* __restrict__ out) {
  int i = blockIdx.x * 256 + threadIdx.x;
  if (i < NN * 64) out[i] = 1000.0f;
}

extern "C" void kernel_launch(void* const* d_in, const int* in_sizes, int n_in,
                              void* d_out, int out_size, void* d_ws, size_t ws_size,
                              hipStream_t stream) {
  const float* x      = (const float*)d_in[0];
  const int*   ei     = (const int*)d_in[1];
  const float* pseudo = (const float*)d_in[2];
  const float* w      = (const float*)d_in[3];
  const float* root   = (const float*)d_in[4];
  const float* bias   = (const float*)d_in[5];
  float* out = (float*)d_out;
  (void)in_sizes; (void)n_in; (void)out_size;

  char* ws = (char*)d_ws;
  size_t off = 0;
  auto alloc = [&](size_t bytes) { size_t r = off; off += (bytes + 511) & ~(size_t)511; return r; };
  ushort_t* wt     = (ushort_t*)(ws + alloc((size_t)64 * KD * 2));          // 213 KB
  int*      ccur   = (int*)(ws + alloc((size_t)NB * NSH * CSTR * 4));       // 100 KB
  uint2*    nfo    = (uint2*)(ws + alloc((size_t)NN * 8));                  // 400 KB
  uint2*    recs   = (uint2*)(ws + alloc((size_t)EE * 8));                  // 12.8 MB
  uint2*    coarse = (uint2*)(ws + alloc((size_t)NB * NSH * CCAP * 8));     // 16.0 MB
  size_t baseNeed  = off;
  ushort_t* xb     = (ushort_t*)(ws + alloc((size_t)NN * 64 * 2));          // 6.4 MB (optional)
  size_t fullNeed  = off;

  if (ws_size < baseNeed) {
    k_sentinel<<<(NN * 64 + 255) / 256, 256, 0, stream>>>(out);
    return;
  }
  const int useXB = (ws_size >= fullNeed) ? 1 : 0;

  hipMemsetAsync(ccur, 0, (size_t)NB * NSH * CSTR * 4, stream);
  k_prep<<<REC_B + XB_B + WT_B, 256, 0, stream>>>(ei, pseudo, ccur, coarse,
                                                  x, xb, w, root, wt, useXB);
  k_sort<<<NB, 256, 0, stream>>>(ccur, coarse, recs, nfo);
  if (useXB)
    k_main<true><<<NN / NPB, 512, 0, stream>>>(recs, nfo, x, xb, wt, bias, out);
  else
    k_main<false><<<NN / NPB, 512, 0, stream>>>(recs, nfo, x, xb, wt, bias, out);
}